// Round 7
// baseline (1528.275 us; speedup 1.0000x reference)
//
#include <hip/hip_runtime.h>
#include <math.h>

// Problem constants (match reference)
#define N_NODES 50000
#define N_EDGES 800000
#define RELS    3
#define HID     64
#define S_SEEDS 8192
#define OUT_COLS 321   // 1 (pred_missing) + 320 (pred_feat)
#define S_CH    4096   // seed-chunk for the 2048-wide f-branch hidden layer
#define NB      391    // buckets of 128 nodes: ceil(50000/128)
#define BCAP    2560   // per-(rel,bucket) edge capacity (mean 2046, +11 sigma)
#define CHUNK   4096   // edges per bin_fill block
#define NCHUNK  196    // ceil(800000/4096)

// fp16 everywhere (NOT bf16): all network values are tiny (|v| < ~10,
// weights ~0.05) so fp16's range is safe, and its 10 mantissa bits cut the
// GEMM input-rounding error 4x vs bf16 — R6 failed at absmax 0.023 vs
// threshold 0.0195 purely on the bf16 2^-8 product-rounding tail.
typedef __attribute__((ext_vector_type(8))) _Float16 v8h;  // 8 f16 in 4 VGPRs
typedef __attribute__((ext_vector_type(4))) float v4f;     // MFMA accumulator

__device__ __forceinline__ unsigned short f32_to_f16(float f) {
    _Float16 h = (_Float16)f;                 // v_cvt_f16_f32, RTN-even
    return __builtin_bit_cast(unsigned short, h);
}
__device__ __forceinline__ float f16_to_f32(unsigned short u) {
    return (float)__builtin_bit_cast(_Float16, u);
}

// ---------------------------------------------------------------------------
// fp16 MFMA GEMM: C = act(A @ Bt^T + bias) [+ noise]
// A : M x K f16 row-major (lda); Bt: N x K f16 (B pre-transposed)
// Block 256 = 4 waves; tile 128x128; BK=32. Staging: 2 threads/row x 32 B.
// ACT: 0=none 1=relu 2=leaky(0.01) 3=tanh. noise (f32, stride ldc) added after act.
// ---------------------------------------------------------------------------
template<int ACT, bool OUT_F16>
__global__ __launch_bounds__(256) void gemm_mfma_f16(
    const unsigned short* __restrict__ A, long long sAb, int lda,
    const unsigned short* __restrict__ Bt, long long sBb,
    const float* __restrict__ bias, long long sBiasb,
    void* __restrict__ Cv, long long sCb, int ldc,
    const float* __restrict__ noise,
    int M, int Nc, int K)
{
    __shared__ __align__(16) unsigned short As[128][40];
    __shared__ __align__(16) unsigned short Bs[128][40];

    const int r = blockIdx.z;
    A  += (long long)r * sAb;
    Bt += (long long)r * sBb;
    const float* brow = bias ? bias + (long long)r * sBiasb : nullptr;

    const int tid  = threadIdx.x;
    const int wave = tid >> 6, lane = tid & 63;
    const int quad = lane >> 4, l16 = lane & 15;
    const int wrow = (wave >> 1) * 64, wcol = (wave & 1) * 64;
    const int row0 = blockIdx.y * 128, col0 = blockIdx.x * 128;

    v4f acc[4][4] = {};

    const int srow = tid >> 1;            // 0..127
    const int ecol = (tid & 1) * 16;      // each thread stages 16 f16 = 32 B

    for (int k0 = 0; k0 < K; k0 += 32) {
        int gr = row0 + srow;
        int4 a0 = make_int4(0, 0, 0, 0), a1 = make_int4(0, 0, 0, 0);
        if (gr < M) {
            const unsigned short* ap = A + (long long)gr * lda + k0 + ecol;
            a0 = *(const int4*)(ap);
            a1 = *(const int4*)(ap + 8);
        }
        *(int4*)(&As[srow][ecol])     = a0;
        *(int4*)(&As[srow][ecol + 8]) = a1;

        int gn = col0 + srow;
        int4 b0 = make_int4(0, 0, 0, 0), b1 = make_int4(0, 0, 0, 0);
        if (gn < Nc) {
            const unsigned short* bp = Bt + (long long)gn * K + k0 + ecol;
            b0 = *(const int4*)(bp);
            b1 = *(const int4*)(bp + 8);
        }
        *(int4*)(&Bs[srow][ecol])     = b0;
        *(int4*)(&Bs[srow][ecol + 8]) = b1;
        __syncthreads();

        v8h af[4], bfr[4];
#pragma unroll
        for (int i = 0; i < 4; i++)
            af[i] = *(const v8h*)(&As[wrow + i * 16 + l16][quad * 8]);
#pragma unroll
        for (int j = 0; j < 4; j++)
            bfr[j] = *(const v8h*)(&Bs[wcol + j * 16 + l16][quad * 8]);
#pragma unroll
        for (int i = 0; i < 4; i++)
#pragma unroll
            for (int j = 0; j < 4; j++)
                acc[i][j] = __builtin_amdgcn_mfma_f32_16x16x32_f16(af[i], bfr[j], acc[i][j], 0, 0, 0);
        __syncthreads();
    }

    float* Cf = (float*)Cv + (long long)r * sCb;
    unsigned short* Ch = (unsigned short*)Cv + (long long)r * sCb;
#pragma unroll
    for (int i = 0; i < 4; i++) {
#pragma unroll
        for (int j = 0; j < 4; j++) {
            int gc = col0 + wcol + j * 16 + l16;
            if (gc >= Nc) continue;
            float bv = brow ? brow[gc] : 0.f;
#pragma unroll
            for (int t = 0; t < 4; t++) {
                int gr = row0 + wrow + i * 16 + quad * 4 + t;
                if (gr >= M) continue;
                float v = acc[i][j][t] + bv;
                if (ACT == 1)      v = fmaxf(v, 0.f);
                else if (ACT == 2) v = (v > 0.f) ? v : 0.01f * v;
                else if (ACT == 3) v = tanhf(v);
                if (noise) v += noise[(long long)gr * ldc + gc];
                if (OUT_F16) Ch[(long long)gr * ldc + gc] = f32_to_f16(v);
                else         Cf[(long long)gr * ldc + gc] = v;
            }
        }
    }
}

// ---------------------------------------------------------------------------
// Prep kernels
// ---------------------------------------------------------------------------
__global__ void cvt_f32_f16_kernel(const float* __restrict__ src,
                                   unsigned short* __restrict__ dst, long long n)
{
    long long i = (long long)blockIdx.x * blockDim.x + threadIdx.x;
    if (i < n) dst[i] = f32_to_f16(src[i]);
}

// Tiled transpose+cvt: src (R, K, N) f32 -> dst (R, N, K) f16. Coalesced both sides.
__global__ __launch_bounds__(256) void transpose_f16_kernel(
    const float* __restrict__ src, unsigned short* __restrict__ dst, int K, int N)
{
    __shared__ float t[32][33];
    int r = blockIdx.z;
    src += (long long)r * K * N;
    dst += (long long)r * K * N;
    int n0 = blockIdx.x * 32, k0 = blockIdx.y * 32;
    int tx = threadIdx.x & 31, ty = threadIdx.x >> 5;   // (32, 8)
#pragma unroll
    for (int i = 0; i < 32; i += 8) {
        int k = k0 + ty + i, n = n0 + tx;
        if (k < K && n < N) t[ty + i][tx] = src[(long long)k * N + n];
    }
    __syncthreads();
#pragma unroll
    for (int i = 0; i < 32; i += 8) {
        int n = n0 + ty + i, k = k0 + tx;
        if (n < N && k < K) dst[(long long)n * K + k] = f32_to_f16(t[tx][ty + i]);
    }
}

// ---------------------------------------------------------------------------
// bin_fill: bin edges by dst>>7 into per-(rel,bucket) runs with block-local
// sort + bulk reservation. Writes are contiguous runs (full-line coalesced) —
// replaces the fine counting sort whose random 4B scatters cost 160 MB of
// HBM writeback (R5 counters: 66 B written back per 4 B store).
// Packed entry: (dst&127)<<16 | src  (src < 50000 < 2^16).
// ---------------------------------------------------------------------------
__global__ __launch_bounds__(256) void bin_fill_kernel(
    const int* __restrict__ s0, const int* __restrict__ d0,
    const int* __restrict__ s1, const int* __restrict__ d1,
    const int* __restrict__ s2, const int* __restrict__ d2,
    int* __restrict__ gcursor,            // (RELS*NB), pre-zeroed
    unsigned int* __restrict__ bedges)    // (RELS*NB, BCAP)
{
    __shared__ int cnt[NB];
    __shared__ int lstart[NB];
    __shared__ int fillc[NB];
    __shared__ int gstart[NB];
    __shared__ int scan[512];
    __shared__ unsigned int svals[CHUNK];
    __shared__ short sbuck[CHUNK];

    const int rel = blockIdx.y;
    const int* sp = (rel == 0) ? s0 : (rel == 1) ? s1 : s2;
    const int* dp = (rel == 0) ? d0 : (rel == 1) ? d1 : d2;
    const int tid = threadIdx.x;
    const int e0 = blockIdx.x * CHUNK;
    const int n  = min(CHUNK, N_EDGES - e0);

    for (int i = tid; i < NB; i += 256) { cnt[i] = 0; fillc[i] = 0; }
    __syncthreads();

    int myb[CHUNK / 256];
    unsigned int myv[CHUNK / 256];
#pragma unroll
    for (int i = 0; i < CHUNK / 256; i++) {
        int off = tid + i * 256;
        if (off < n) {
            int e = e0 + off;
            int s = sp[e], d = dp[e];
            int b = d >> 7;
            myb[i] = b;
            myv[i] = ((unsigned int)(d & 127) << 16) | (unsigned int)s;
            atomicAdd(&cnt[b], 1);
        } else myb[i] = -1;
    }
    __syncthreads();

    // inclusive scan of cnt over 512 (padded), 2 elements/thread
    scan[tid]       = (tid < NB) ? cnt[tid] : 0;
    scan[tid + 256] = (tid + 256 < NB) ? cnt[tid + 256] : 0;
    __syncthreads();
    for (int off = 1; off < 512; off <<= 1) {
        int a = (tid >= off) ? scan[tid - off] : 0;
        int b = (tid + 256 >= off) ? scan[tid + 256 - off] : 0;
        __syncthreads();
        scan[tid] += a; scan[tid + 256] += b;
        __syncthreads();
    }
    if (tid < NB)       lstart[tid]       = scan[tid] - cnt[tid];
    if (tid + 256 < NB) lstart[tid + 256] = scan[tid + 256] - cnt[tid + 256];
    __syncthreads();

    // block-local bucket-sorted placement
#pragma unroll
    for (int i = 0; i < CHUNK / 256; i++) {
        int b = myb[i];
        if (b >= 0) {
            int p = lstart[b] + atomicAdd(&fillc[b], 1);
            svals[p] = myv[i];
            sbuck[p] = (short)b;
        }
    }
    // bulk global reservation (one atomic per non-empty bucket)
    if (tid < NB && cnt[tid] > 0)
        gstart[tid] = atomicAdd(&gcursor[rel * NB + tid], cnt[tid]);
    if (tid + 256 < NB && cnt[tid + 256] > 0)
        gstart[tid + 256] = atomicAdd(&gcursor[rel * NB + tid + 256], cnt[tid + 256]);
    __syncthreads();

    // contiguous run copy-out
    for (int p = tid; p < n; p += 256) {
        int b = sbuck[p];
        int pos = gstart[b] + (p - lstart[b]);
        bedges[(long long)(rel * NB + b) * BCAP + pos] = svals[p];
    }
}

// ---------------------------------------------------------------------------
// binned_agg: one block per (bucket, rel). LDS f32 accumulation over the
// bucket's 128 nodes; degrees counted in-block (no hist/scan needed).
// agg[d][rel*64+lane] = f16( (1/max(deg,1)) * sum feat[src][lane] )
// ---------------------------------------------------------------------------
__global__ __launch_bounds__(256) void binned_agg_kernel(
    const unsigned short* __restrict__ feat,   // (*, 64) f16
    const unsigned int* __restrict__ bedges,   // (RELS*NB, BCAP)
    const int* __restrict__ gcursor,           // (RELS*NB) = bucket lengths
    unsigned short* __restrict__ agg,          // (M, 192) f16
    int M)
{
    __shared__ float sagg[128][64];
    __shared__ int scnt[128];

    const int bucket = blockIdx.x, rel = blockIdx.y;
    const int tid = threadIdx.x, wave = tid >> 6, lane = tid & 63;

    float* sf = &sagg[0][0];
    for (int i = tid; i < 128 * 64; i += 256) sf[i] = 0.f;
    for (int i = tid; i < 128; i += 256) scnt[i] = 0;
    __syncthreads();

    const int len = gcursor[rel * NB + bucket];
    const unsigned int* ep = bedges + (long long)(rel * NB + bucket) * BCAP;

    for (int e = wave * 2; e < len; e += 8) {
        unsigned int v0 = ep[e];
        bool has1 = (e + 1 < len);
        unsigned int v1 = has1 ? ep[e + 1] : 0u;
        int src0 = v0 & 0xFFFF, dl0 = v0 >> 16;
        float f0 = f16_to_f32(feat[(long long)src0 * HID + lane]);
        float f1 = 0.f; int dl1 = 0;
        if (has1) {
            int src1 = v1 & 0xFFFF; dl1 = v1 >> 16;
            f1 = f16_to_f32(feat[(long long)src1 * HID + lane]);
        }
        atomicAdd(&sagg[dl0][lane], f0);
        if (lane == 0) atomicAdd(&scnt[dl0], 1);
        if (has1) {
            atomicAdd(&sagg[dl1][lane], f1);
            if (lane == 0) atomicAdd(&scnt[dl1], 1);
        }
    }
    __syncthreads();

#pragma unroll
    for (int k = 0; k < 32; k++) {
        int nloc = wave + k * 4;
        int d = bucket * 128 + nloc;
        if (d >= M) continue;
        float inv = 1.0f / fmaxf((float)scnt[nloc], 1.0f);
        agg[(long long)d * (RELS * HID) + rel * HID + lane] =
            f32_to_f16(sagg[nloc][lane] * inv);
    }
}

// ---------------------------------------------------------------------------
// d-branch final head: out[r,s,0] = relu(z2d[r,s,:] . dW3[r] + db3[r])
// ---------------------------------------------------------------------------
__global__ void dhead_kernel(const float* __restrict__ z2d,
                             const float* __restrict__ dW3,
                             const float* __restrict__ db3,
                             float* __restrict__ out)
{
    int idx = blockIdx.x * blockDim.x + threadIdx.x;
    if (idx >= RELS * S_SEEDS) return;
    int r = idx / S_SEEDS;
    const float* zp = z2d + (long long)idx * 32;
    const float* wp = dW3 + r * 32;
    float acc = db3[r];
#pragma unroll
    for (int k = 0; k < 32; k++) acc += zp[k] * wp[k];
    out[(long long)idx * OUT_COLS] = fmaxf(acc, 0.f);
}

// ---------------------------------------------------------------------------
extern "C" void kernel_launch(void* const* d_in, const int* in_sizes, int n_in,
                              void* d_out, int out_size, void* d_ws, size_t ws_size,
                              hipStream_t stream)
{
    const float* x     = (const float*)d_in[0];
    const float* noise = (const float*)d_in[1];
    // d_in[2] = seeds: only its shape matters (S=8192); unused.
    const int* srcs[RELS] = { (const int*)d_in[3], (const int*)d_in[5], (const int*)d_in[7] };
    const int* dsts[RELS] = { (const int*)d_in[4], (const int*)d_in[6], (const int*)d_in[8] };
    const float* Wc1  = (const float*)d_in[9];   // (3,64,64) == stacked (192,64)
    const float* bc1  = (const float*)d_in[10];
    const float* Wc2  = (const float*)d_in[11];
    const float* bc2  = (const float*)d_in[12];
    const float* Wlin = (const float*)d_in[13];
    const float* blin = (const float*)d_in[14];
    const float* dW1  = (const float*)d_in[15];
    const float* db1  = (const float*)d_in[16];
    const float* dW2  = (const float*)d_in[17];
    const float* db2  = (const float*)d_in[18];
    const float* dW3  = (const float*)d_in[19];
    const float* db3  = (const float*)d_in[20];
    const float* fW1  = (const float*)d_in[21];
    const float* fb1  = (const float*)d_in[22];
    const float* fW2  = (const float*)d_in[23];
    const float* fb2  = (const float*)d_in[24];
    const float* fW3  = (const float*)d_in[25];
    const float* fb3  = (const float*)d_in[26];
    float* out = (float*)d_out;
    float* w   = (float*)d_ws;

    // ---- workspace layout (4-byte units; ~82 MB peak, all 16B-aligned) ----
    int* gcursor = (int*)w;                                    // 1,280 (RELS*NB=1173)
    // REGION_A (12,582,912 f) @ w+1280:
    //   aggx_hf  @ A+0        (50000*192 f16 = 2.4M f)    [live: agg1 -> conv1]
    //   bedges   @ A+2.4M     (RELS*NB*BCAP u32 = 3.0M f) [live: fill -> agg2]
    //   z2d      @ A+2.4M     (3*8192*32 f32 = 786k f)    [live: d-branch]
    //   z2hf     @ A+0        (3*4096*2048 f16 = 12.58M f) [live: f-branch chunk]
    unsigned short* aggx_hf = (unsigned short*)(w + 1280);
    unsigned int*   bedges  = (unsigned int*)(w + 1280 + 2400000);
    float*          z2d     = w + 1280 + 2400000;
    unsigned short* z2hf    = (unsigned short*)(w + 1280);
    // REGION_B (3,145,728 f) @ w+12,584,192: xhf (1.6M f) then z1hf
    unsigned short* xhf  = (unsigned short*)(w + 12584192);
    unsigned short* z1hf = (unsigned short*)(w + 12584192);
    unsigned short* h1hf   = (unsigned short*)(w + 15729920);  // 50000*64 f16 = 1.6M f
    unsigned short* agg2hf = (unsigned short*)(w + 17329920);  // 8192*192 f16 = 786k f
    unsigned short* h2shf  = (unsigned short*)(w + 18116352);  // 8192*64 f16
    unsigned short* hshf   = (unsigned short*)(w + 18378496);  // 8192*64 f16
    unsigned short* WcT1   = (unsigned short*)(w + 18640640);  // (64,192) f16
    unsigned short* WcT2   = (unsigned short*)(w + 18646784);  // (64,192) f16
    unsigned short* WlinT  = (unsigned short*)(w + 18652928);  // (64,64) f16
    unsigned short* dW1ht  = (unsigned short*)(w + 18654976);  // (3,256,64) f16
    unsigned short* dW2ht  = (unsigned short*)(w + 18679552);  // (3,32,256) f16
    unsigned short* fW1ht  = (unsigned short*)(w + 18691840);  // (3,256,64) f16
    unsigned short* fW2ht  = (unsigned short*)(w + 18716416);  // (3,2048,256) f16
    unsigned short* fW3ht  = (unsigned short*)(w + 19502848);  // (3,320,2048) f16
    // end: 20,485,888 f = 81.9 MB

    // ---- edge binning (shared by both conv layers; also yields degrees) ----
    hipMemsetAsync(gcursor, 0, (size_t)RELS * NB * sizeof(int), stream);
    bin_fill_kernel<<<dim3(NCHUNK, RELS), 256, 0, stream>>>(
        srcs[0], dsts[0], srcs[1], dsts[1], srcs[2], dsts[2], gcursor, bedges);

    // ---- prep: x -> f16; weights -> transposed f16 ----
    cvt_f32_f16_kernel<<<(N_NODES * HID + 255) / 256, 256, 0, stream>>>(x, xhf, (long long)N_NODES * HID);
    transpose_f16_kernel<<<dim3(2, 6, 1), 256, 0, stream>>>(Wc1, WcT1, 192, 64);
    transpose_f16_kernel<<<dim3(2, 6, 1), 256, 0, stream>>>(Wc2, WcT2, 192, 64);
    transpose_f16_kernel<<<dim3(2, 2, 1), 256, 0, stream>>>(Wlin, WlinT, 64, 64);
    transpose_f16_kernel<<<dim3(8, 2, RELS), 256, 0, stream>>>(dW1, dW1ht, 64, 256);
    transpose_f16_kernel<<<dim3(1, 8, RELS), 256, 0, stream>>>(dW2, dW2ht, 256, 32);
    transpose_f16_kernel<<<dim3(8, 2, RELS), 256, 0, stream>>>(fW1, fW1ht, 64, 256);
    transpose_f16_kernel<<<dim3(64, 8, RELS), 256, 0, stream>>>(fW2, fW2ht, 256, 2048);
    transpose_f16_kernel<<<dim3(10, 64, RELS), 256, 0, stream>>>(fW3, fW3ht, 2048, 320);

    // ---- conv layer 1: binned aggregation of x -> aggx (50000x192), MFMA -> h1hf ----
    binned_agg_kernel<<<dim3(NB, RELS), 256, 0, stream>>>(
        xhf, bedges, gcursor, aggx_hf, N_NODES);
    gemm_mfma_f16<1, true><<<dim3(1, (N_NODES + 127) / 128, 1), 256, 0, stream>>>(
        aggx_hf, 0, RELS * HID, WcT1, 0, bc1, 0,
        h1hf, 0, HID, nullptr, N_NODES, HID, RELS * HID);

    // ---- conv layer 2 (rows < S only => buckets 0..63), MFMA -> h2shf ----
    binned_agg_kernel<<<dim3(S_SEEDS / 128, RELS), 256, 0, stream>>>(
        h1hf, bedges, gcursor, agg2hf, S_SEEDS);
    gemm_mfma_f16<1, true><<<dim3(1, S_SEEDS / 128, 1), 256, 0, stream>>>(
        agg2hf, 0, RELS * HID, WcT2, 0, bc2, 0,
        h2shf, 0, HID, nullptr, S_SEEDS, HID, RELS * HID);

    // ---- hs = leaky(h2s @ Wlin + blin) + noise[:S]  (MFMA, f16 out) ----
    gemm_mfma_f16<2, true><<<dim3(1, S_SEEDS / 128, 1), 256, 0, stream>>>(
        h2shf, 0, HID, WlinT, 0, blin, 0,
        hshf, 0, HID, noise, S_SEEDS, HID, HID);

    // ---- d-branch (MFMA): z1 -> z2d -> dhead ----
    gemm_mfma_f16<2, true><<<dim3(2, S_SEEDS / 128, RELS), 256, 0, stream>>>(
        hshf, 0, HID, dW1ht, 256LL * 64, db1, 256,
        z1hf, (long long)S_SEEDS * 256, 256, nullptr, S_SEEDS, 256, HID);
    gemm_mfma_f16<2, false><<<dim3(1, S_SEEDS / 128, RELS), 256, 0, stream>>>(
        z1hf, (long long)S_SEEDS * 256, 256, dW2ht, 32LL * 256, db2, 32,
        z2d, (long long)S_SEEDS * 32, 32, nullptr, S_SEEDS, 32, 256);
    dhead_kernel<<<(RELS * S_SEEDS + 255) / 256, 256, 0, stream>>>(z2d, dW3, db3, out);

    // ---- f-branch (MFMA): z1 -> chunked (fW2, fW3) ----
    gemm_mfma_f16<1, true><<<dim3(2, S_SEEDS / 128, RELS), 256, 0, stream>>>(
        hshf, 0, HID, fW1ht, 256LL * 64, fb1, 256,
        z1hf, (long long)S_SEEDS * 256, 256, nullptr, S_SEEDS, 256, HID);
    for (int c = 0; c < S_SEEDS / S_CH; c++) {
        long long s0 = (long long)c * S_CH;
        gemm_mfma_f16<1, true><<<dim3(2048 / 128, S_CH / 128, RELS), 256, 0, stream>>>(
            z1hf + s0 * 256, (long long)S_SEEDS * 256, 256,
            fW2ht, 2048LL * 256, fb2, 2048,
            z2hf, (long long)S_CH * 2048, 2048, nullptr, S_CH, 2048, 256);
        gemm_mfma_f16<3, false><<<dim3((320 + 127) / 128, S_CH / 128, RELS), 256, 0, stream>>>(
            z2hf, (long long)S_CH * 2048, 2048,
            fW3ht, 320LL * 2048, fb3, 320,
            out + s0 * OUT_COLS + 1, (long long)S_SEEDS * OUT_COLS, OUT_COLS,
            nullptr, S_CH, 320, 2048);
    }
}

// Round 8
// 680.583 us; speedup vs baseline: 2.2455x; 2.2455x over previous
//
#include <hip/hip_runtime.h>
#include <math.h>

// Problem constants (match reference)
#define N_NODES 50000
#define N_EDGES 800000
#define RELS    3
#define HID     64
#define S_SEEDS 8192
#define OUT_COLS 321   // 1 (pred_missing) + 320 (pred_feat)
#define S_CH    4096   // seed-chunk for the 2048-wide f-branch hidden layer
#define NB      391    // buckets of 128 nodes: ceil(50000/128)
#define BCAP    2560   // per-(rel,bucket) edge capacity (mean 2048, +11 sigma)
#define CHUNK   4096   // edges per bin_fill block
#define NCHUNK  196    // ceil(800000/4096)

// fp16 pipeline (values are tiny: |x|<~6, weights ~0.05 — no range risk;
// 10 mantissa bits vs bf16's 7). R7 learned: LDS-atomic aggregation was both
// 6x slower than CSR gather AND carried the error tail (0.0195 vs R5's 0.0078)
// — this round restores atomic-free CSR gather, built cheaply via coarse
// binning + per-bucket LDS counting sort.
typedef __attribute__((ext_vector_type(8))) _Float16 v8h;  // 8 f16 in 4 VGPRs
typedef __attribute__((ext_vector_type(4))) float v4f;     // MFMA accumulator

__device__ __forceinline__ unsigned short f32_to_f16(float f) {
    _Float16 h = (_Float16)f;                 // v_cvt_f16_f32, RTN-even
    return __builtin_bit_cast(unsigned short, h);
}
__device__ __forceinline__ float f16_to_f32(unsigned short u) {
    return (float)__builtin_bit_cast(_Float16, u);
}

// ---------------------------------------------------------------------------
// fp16 MFMA GEMM: C = act(A @ Bt^T + bias) [+ noise]
// A : M x K f16 row-major (lda); Bt: N x K f16 (B pre-transposed)
// Block 256 = 4 waves; tile 128x128; BK=32. Staging: 2 threads/row x 32 B.
// ACT: 0=none 1=relu 2=leaky(0.01) 3=tanh. noise (f32, stride ldc) added after act.
// ---------------------------------------------------------------------------
template<int ACT, bool OUT_F16>
__global__ __launch_bounds__(256) void gemm_mfma_f16(
    const unsigned short* __restrict__ A, long long sAb, int lda,
    const unsigned short* __restrict__ Bt, long long sBb,
    const float* __restrict__ bias, long long sBiasb,
    void* __restrict__ Cv, long long sCb, int ldc,
    const float* __restrict__ noise,
    int M, int Nc, int K)
{
    __shared__ __align__(16) unsigned short As[128][40];
    __shared__ __align__(16) unsigned short Bs[128][40];

    const int r = blockIdx.z;
    A  += (long long)r * sAb;
    Bt += (long long)r * sBb;
    const float* brow = bias ? bias + (long long)r * sBiasb : nullptr;

    const int tid  = threadIdx.x;
    const int wave = tid >> 6, lane = tid & 63;
    const int quad = lane >> 4, l16 = lane & 15;
    const int wrow = (wave >> 1) * 64, wcol = (wave & 1) * 64;
    const int row0 = blockIdx.y * 128, col0 = blockIdx.x * 128;

    v4f acc[4][4] = {};

    const int srow = tid >> 1;            // 0..127
    const int ecol = (tid & 1) * 16;      // each thread stages 16 f16 = 32 B

    for (int k0 = 0; k0 < K; k0 += 32) {
        int gr = row0 + srow;
        int4 a0 = make_int4(0, 0, 0, 0), a1 = make_int4(0, 0, 0, 0);
        if (gr < M) {
            const unsigned short* ap = A + (long long)gr * lda + k0 + ecol;
            a0 = *(const int4*)(ap);
            a1 = *(const int4*)(ap + 8);
        }
        *(int4*)(&As[srow][ecol])     = a0;
        *(int4*)(&As[srow][ecol + 8]) = a1;

        int gn = col0 + srow;
        int4 b0 = make_int4(0, 0, 0, 0), b1 = make_int4(0, 0, 0, 0);
        if (gn < Nc) {
            const unsigned short* bp = Bt + (long long)gn * K + k0 + ecol;
            b0 = *(const int4*)(bp);
            b1 = *(const int4*)(bp + 8);
        }
        *(int4*)(&Bs[srow][ecol])     = b0;
        *(int4*)(&Bs[srow][ecol + 8]) = b1;
        __syncthreads();

        v8h af[4], bfr[4];
#pragma unroll
        for (int i = 0; i < 4; i++)
            af[i] = *(const v8h*)(&As[wrow + i * 16 + l16][quad * 8]);
#pragma unroll
        for (int j = 0; j < 4; j++)
            bfr[j] = *(const v8h*)(&Bs[wcol + j * 16 + l16][quad * 8]);
#pragma unroll
        for (int i = 0; i < 4; i++)
#pragma unroll
            for (int j = 0; j < 4; j++)
                acc[i][j] = __builtin_amdgcn_mfma_f32_16x16x32_f16(af[i], bfr[j], acc[i][j], 0, 0, 0);
        __syncthreads();
    }

    float* Cf = (float*)Cv + (long long)r * sCb;
    unsigned short* Ch = (unsigned short*)Cv + (long long)r * sCb;
#pragma unroll
    for (int i = 0; i < 4; i++) {
#pragma unroll
        for (int j = 0; j < 4; j++) {
            int gc = col0 + wcol + j * 16 + l16;
            if (gc >= Nc) continue;
            float bv = brow ? brow[gc] : 0.f;
#pragma unroll
            for (int t = 0; t < 4; t++) {
                int gr = row0 + wrow + i * 16 + quad * 4 + t;
                if (gr >= M) continue;
                float v = acc[i][j][t] + bv;
                if (ACT == 1)      v = fmaxf(v, 0.f);
                else if (ACT == 2) v = (v > 0.f) ? v : 0.01f * v;
                else if (ACT == 3) v = tanhf(v);
                if (noise) v += noise[(long long)gr * ldc + gc];
                if (OUT_F16) Ch[(long long)gr * ldc + gc] = f32_to_f16(v);
                else         Cf[(long long)gr * ldc + gc] = v;
            }
        }
    }
}

// ---------------------------------------------------------------------------
// Prep kernels
// ---------------------------------------------------------------------------
__global__ void cvt_f32_f16_kernel(const float* __restrict__ src,
                                   unsigned short* __restrict__ dst, long long n)
{
    long long i = (long long)blockIdx.x * blockDim.x + threadIdx.x;
    if (i < n) dst[i] = f32_to_f16(src[i]);
}

// Tiled transpose+cvt: src (R, K, N) f32 -> dst (R, N, K) f16. Coalesced both sides.
__global__ __launch_bounds__(256) void transpose_f16_kernel(
    const float* __restrict__ src, unsigned short* __restrict__ dst, int K, int N)
{
    __shared__ float t[32][33];
    int r = blockIdx.z;
    src += (long long)r * K * N;
    dst += (long long)r * K * N;
    int n0 = blockIdx.x * 32, k0 = blockIdx.y * 32;
    int tx = threadIdx.x & 31, ty = threadIdx.x >> 5;   // (32, 8)
#pragma unroll
    for (int i = 0; i < 32; i += 8) {
        int k = k0 + ty + i, n = n0 + tx;
        if (k < K && n < N) t[ty + i][tx] = src[(long long)k * N + n];
    }
    __syncthreads();
#pragma unroll
    for (int i = 0; i < 32; i += 8) {
        int n = n0 + ty + i, k = k0 + tx;
        if (n < N && k < K) dst[(long long)n * K + k] = f32_to_f16(t[tx][ty + i]);
    }
}

// ---------------------------------------------------------------------------
// bin_fill: bin edges by dst>>7 into per-(rel,bucket) runs with block-local
// sort + bulk reservation; all global writes are contiguous runs (coalesced).
// Packed entry: (dst&127)<<16 | src  (src < 50000 < 2^16).
// ---------------------------------------------------------------------------
__global__ __launch_bounds__(256) void bin_fill_kernel(
    const int* __restrict__ s0, const int* __restrict__ d0,
    const int* __restrict__ s1, const int* __restrict__ d1,
    const int* __restrict__ s2, const int* __restrict__ d2,
    int* __restrict__ gcursor,            // (RELS*NB), pre-zeroed
    unsigned int* __restrict__ bedges)    // (RELS*NB, BCAP)
{
    __shared__ int cnt[NB];
    __shared__ int lstart[NB];
    __shared__ int fillc[NB];
    __shared__ int gstart[NB];
    __shared__ int scan[512];
    __shared__ unsigned int svals[CHUNK];
    __shared__ short sbuck[CHUNK];

    const int rel = blockIdx.y;
    const int* sp = (rel == 0) ? s0 : (rel == 1) ? s1 : s2;
    const int* dp = (rel == 0) ? d0 : (rel == 1) ? d1 : d2;
    const int tid = threadIdx.x;
    const int e0 = blockIdx.x * CHUNK;
    const int n  = min(CHUNK, N_EDGES - e0);

    for (int i = tid; i < NB; i += 256) { cnt[i] = 0; fillc[i] = 0; }
    __syncthreads();

    int myb[CHUNK / 256];
    unsigned int myv[CHUNK / 256];
#pragma unroll
    for (int i = 0; i < CHUNK / 256; i++) {
        int off = tid + i * 256;
        if (off < n) {
            int e = e0 + off;
            int s = sp[e], d = dp[e];
            int b = d >> 7;
            myb[i] = b;
            myv[i] = ((unsigned int)(d & 127) << 16) | (unsigned int)s;
            atomicAdd(&cnt[b], 1);
        } else myb[i] = -1;
    }
    __syncthreads();

    // inclusive scan of cnt over 512 (padded), 2 elements/thread
    scan[tid]       = (tid < NB) ? cnt[tid] : 0;
    scan[tid + 256] = (tid + 256 < NB) ? cnt[tid + 256] : 0;
    __syncthreads();
    for (int off = 1; off < 512; off <<= 1) {
        int a = (tid >= off) ? scan[tid - off] : 0;
        int b = (tid + 256 >= off) ? scan[tid + 256 - off] : 0;
        __syncthreads();
        scan[tid] += a; scan[tid + 256] += b;
        __syncthreads();
    }
    if (tid < NB)       lstart[tid]       = scan[tid] - cnt[tid];
    if (tid + 256 < NB) lstart[tid + 256] = scan[tid + 256] - cnt[tid + 256];
    __syncthreads();

    // block-local bucket-sorted placement
#pragma unroll
    for (int i = 0; i < CHUNK / 256; i++) {
        int b = myb[i];
        if (b >= 0) {
            int p = lstart[b] + atomicAdd(&fillc[b], 1);
            svals[p] = myv[i];
            sbuck[p] = (short)b;
        }
    }
    // bulk global reservation (one atomic per non-empty bucket)
    if (tid < NB && cnt[tid] > 0)
        gstart[tid] = atomicAdd(&gcursor[rel * NB + tid], cnt[tid]);
    if (tid + 256 < NB && cnt[tid + 256] > 0)
        gstart[tid + 256] = atomicAdd(&gcursor[rel * NB + tid + 256], cnt[tid + 256]);
    __syncthreads();

    // contiguous run copy-out
    for (int p = tid; p < n; p += 256) {
        int b = sbuck[p];
        int pos = gstart[b] + (p - lstart[b]);
        bedges[(long long)(rel * NB + b) * BCAP + pos] = svals[p];
    }
}

// ---------------------------------------------------------------------------
// bucket_csr: per (rel,bucket) LDS counting sort of the bucket's edges ->
// dst-sorted src list (u16, coalesced write) + 128 local row starts.
// ---------------------------------------------------------------------------
__global__ __launch_bounds__(256) void bucket_csr_kernel(
    const unsigned int* __restrict__ bedges,   // (RELS*NB, BCAP) packed
    const int* __restrict__ gcursor,           // (RELS*NB) lengths
    unsigned short* __restrict__ csr16,        // (RELS*NB, BCAP) sorted srcs
    int* __restrict__ browptr)                 // (RELS*NB, 128) local starts
{
    __shared__ int cnt[128], sc[128], start[128], cur[128];
    __shared__ unsigned short ssorted[BCAP];

    const int id  = blockIdx.y * NB + blockIdx.x;   // rel*NB + bucket
    const int tid = threadIdx.x;
    const int len = gcursor[id];
    const unsigned int* ep = bedges + (long long)id * BCAP;

    for (int i = tid; i < 128; i += 256) cnt[i] = 0;
    __syncthreads();
    for (int i = tid; i < len; i += 256)
        atomicAdd(&cnt[ep[i] >> 16], 1);
    __syncthreads();

    int v = (tid < 128) ? cnt[tid] : 0;
    if (tid < 128) sc[tid] = v;
    __syncthreads();
    for (int off = 1; off < 128; off <<= 1) {
        int a = (tid < 128 && tid >= off) ? sc[tid - off] : 0;
        __syncthreads();
        if (tid < 128) sc[tid] += a;
        __syncthreads();
    }
    if (tid < 128) { start[tid] = sc[tid] - v; cur[tid] = sc[tid] - v; }
    __syncthreads();

    for (int i = tid; i < len; i += 256) {
        unsigned int vv = ep[i];
        int dl = vv >> 16;
        int pos = atomicAdd(&cur[dl], 1);
        ssorted[pos] = (unsigned short)(vv & 0xFFFFu);
    }
    __syncthreads();

    for (int i = tid; i < len; i += 256)
        csr16[(long long)id * BCAP + i] = ssorted[i];
    if (tid < 128) browptr[id * 128 + tid] = start[tid];
}

// ---------------------------------------------------------------------------
// gather_csr_f16: one wave per (node, relation); lane = feature. Register
// accumulation, 4x-unrolled independent loads, zero atomics.
// agg[d][r*64+lane] = f16( (1/max(deg,1)) * sum feat[src][lane] )
// ---------------------------------------------------------------------------
__global__ __launch_bounds__(256) void gather_csr_f16_kernel(
    const unsigned short* __restrict__ feat,   // (*, 64) f16
    const unsigned short* __restrict__ csr16,  // (RELS*NB, BCAP)
    const int* __restrict__ browptr,           // (RELS*NB, 128)
    const int* __restrict__ gcursor,           // (RELS*NB)
    unsigned short* __restrict__ agg,          // (M, 192) f16
    int M)
{
    int w = (blockIdx.x * 256 + threadIdx.x) >> 6;
    int lane = threadIdx.x & 63;
    if (w >= M * RELS) return;
    int r = w % RELS, d = w / RELS;
    int bucket = d >> 7, dl = d & 127;
    int id = r * NB + bucket;
    int p0 = browptr[id * 128 + dl];
    int p1 = (dl == 127) ? gcursor[id] : browptr[id * 128 + dl + 1];
    const unsigned short* cp = csr16 + (long long)id * BCAP;

    float acc0 = 0.f, acc1 = 0.f, acc2 = 0.f, acc3 = 0.f;
    int i = p0;
    for (; i + 3 < p1; i += 4) {
        int s0 = cp[i], s1 = cp[i + 1], s2 = cp[i + 2], s3 = cp[i + 3];
        acc0 += f16_to_f32(feat[(long long)s0 * HID + lane]);
        acc1 += f16_to_f32(feat[(long long)s1 * HID + lane]);
        acc2 += f16_to_f32(feat[(long long)s2 * HID + lane]);
        acc3 += f16_to_f32(feat[(long long)s3 * HID + lane]);
    }
    for (; i < p1; i++) acc0 += f16_to_f32(feat[(long long)cp[i] * HID + lane]);

    float inv = 1.0f / fmaxf((float)(p1 - p0), 1.0f);
    agg[(long long)d * (RELS * HID) + r * HID + lane] =
        f32_to_f16((acc0 + acc1 + acc2 + acc3) * inv);
}

// ---------------------------------------------------------------------------
// d-branch final head: out[r,s,0] = relu(z2d[r,s,:] . dW3[r] + db3[r])
// ---------------------------------------------------------------------------
__global__ void dhead_kernel(const float* __restrict__ z2d,
                             const float* __restrict__ dW3,
                             const float* __restrict__ db3,
                             float* __restrict__ out)
{
    int idx = blockIdx.x * blockDim.x + threadIdx.x;
    if (idx >= RELS * S_SEEDS) return;
    int r = idx / S_SEEDS;
    const float* zp = z2d + (long long)idx * 32;
    const float* wp = dW3 + r * 32;
    float acc = db3[r];
#pragma unroll
    for (int k = 0; k < 32; k++) acc += zp[k] * wp[k];
    out[(long long)idx * OUT_COLS] = fmaxf(acc, 0.f);
}

// ---------------------------------------------------------------------------
extern "C" void kernel_launch(void* const* d_in, const int* in_sizes, int n_in,
                              void* d_out, int out_size, void* d_ws, size_t ws_size,
                              hipStream_t stream)
{
    const float* x     = (const float*)d_in[0];
    const float* noise = (const float*)d_in[1];
    // d_in[2] = seeds: only its shape matters (S=8192); unused.
    const int* srcs[RELS] = { (const int*)d_in[3], (const int*)d_in[5], (const int*)d_in[7] };
    const int* dsts[RELS] = { (const int*)d_in[4], (const int*)d_in[6], (const int*)d_in[8] };
    const float* Wc1  = (const float*)d_in[9];   // (3,64,64) == stacked (192,64)
    const float* bc1  = (const float*)d_in[10];
    const float* Wc2  = (const float*)d_in[11];
    const float* bc2  = (const float*)d_in[12];
    const float* Wlin = (const float*)d_in[13];
    const float* blin = (const float*)d_in[14];
    const float* dW1  = (const float*)d_in[15];
    const float* db1  = (const float*)d_in[16];
    const float* dW2  = (const float*)d_in[17];
    const float* db2  = (const float*)d_in[18];
    const float* dW3  = (const float*)d_in[19];
    const float* db3  = (const float*)d_in[20];
    const float* fW1  = (const float*)d_in[21];
    const float* fb1  = (const float*)d_in[22];
    const float* fW2  = (const float*)d_in[23];
    const float* fb2  = (const float*)d_in[24];
    const float* fW3  = (const float*)d_in[25];
    const float* fb3  = (const float*)d_in[26];
    float* out = (float*)d_out;
    float* w   = (float*)d_ws;

    // ---- workspace layout (4-byte units; ~88.5 MB peak, all 16B-aligned) ----
    int* gcursor = (int*)w;                                     // 1,280 (RELS*NB=1173)
    int* browptr = (int*)(w + 1280);                            // RELS*NB*128 = 150,144
    unsigned short* csr16 = (unsigned short*)(w + 151424);      // RELS*NB*BCAP u16 = 1,501,440 f
    // REGION_A (12,582,912 f) @ w+1,652,864:
    //   aggx_hf @ A+0        (50000*192 f16 = 2.4M f)     [gather1 -> conv1]
    //   bedges  @ A+2.4M     (RELS*NB*BCAP u32 = 3.00M f) [bin_fill -> bucket_csr]
    //   z2d     @ A+2.4M     (3*8192*32 f32 = 786k f)     [d-branch, bedges dead]
    //   z2hf    @ A+0        (3*4096*2048 f16 = 12.58M f) [f-branch chunk]
    unsigned short* aggx_hf = (unsigned short*)(w + 1652864);
    unsigned int*   bedges  = (unsigned int*)(w + 1652864 + 2400000);
    float*          z2d     = w + 1652864 + 2400000;
    unsigned short* z2hf    = (unsigned short*)(w + 1652864);
    // REGION_B (3,145,728 f) @ w+14,235,776: xhf (1.6M f, dead after gather1) then z1hf
    unsigned short* xhf  = (unsigned short*)(w + 14235776);
    unsigned short* z1hf = (unsigned short*)(w + 14235776);
    unsigned short* h1hf   = (unsigned short*)(w + 17381504);  // 50000*64 f16 = 1.6M f
    unsigned short* agg2hf = (unsigned short*)(w + 18981504);  // 8192*192 f16 = 786k f
    unsigned short* h2shf  = (unsigned short*)(w + 19767936);  // 8192*64 f16
    unsigned short* hshf   = (unsigned short*)(w + 20030080);  // 8192*64 f16
    unsigned short* WcT1   = (unsigned short*)(w + 20292224);  // (64,192) f16
    unsigned short* WcT2   = (unsigned short*)(w + 20298368);  // (64,192) f16
    unsigned short* WlinT  = (unsigned short*)(w + 20304512);  // (64,64) f16
    unsigned short* dW1ht  = (unsigned short*)(w + 20306560);  // (3,256,64) f16
    unsigned short* dW2ht  = (unsigned short*)(w + 20331136);  // (3,32,256) f16
    unsigned short* fW1ht  = (unsigned short*)(w + 20343424);  // (3,256,64) f16
    unsigned short* fW2ht  = (unsigned short*)(w + 20368000);  // (3,2048,256) f16
    unsigned short* fW3ht  = (unsigned short*)(w + 21154432);  // (3,320,2048) f16
    // end: 22,137,472 f = 88.5 MB

    // ---- edge binning + per-bucket CSR (shared by both conv layers) ----
    hipMemsetAsync(gcursor, 0, (size_t)RELS * NB * sizeof(int), stream);
    bin_fill_kernel<<<dim3(NCHUNK, RELS), 256, 0, stream>>>(
        srcs[0], dsts[0], srcs[1], dsts[1], srcs[2], dsts[2], gcursor, bedges);
    bucket_csr_kernel<<<dim3(NB, RELS), 256, 0, stream>>>(
        bedges, gcursor, csr16, browptr);

    // ---- prep: x -> f16; weights -> transposed f16 ----
    cvt_f32_f16_kernel<<<(N_NODES * HID + 255) / 256, 256, 0, stream>>>(x, xhf, (long long)N_NODES * HID);
    transpose_f16_kernel<<<dim3(2, 6, 1), 256, 0, stream>>>(Wc1, WcT1, 192, 64);
    transpose_f16_kernel<<<dim3(2, 6, 1), 256, 0, stream>>>(Wc2, WcT2, 192, 64);
    transpose_f16_kernel<<<dim3(2, 2, 1), 256, 0, stream>>>(Wlin, WlinT, 64, 64);
    transpose_f16_kernel<<<dim3(8, 2, RELS), 256, 0, stream>>>(dW1, dW1ht, 64, 256);
    transpose_f16_kernel<<<dim3(1, 8, RELS), 256, 0, stream>>>(dW2, dW2ht, 256, 32);
    transpose_f16_kernel<<<dim3(8, 2, RELS), 256, 0, stream>>>(fW1, fW1ht, 64, 256);
    transpose_f16_kernel<<<dim3(64, 8, RELS), 256, 0, stream>>>(fW2, fW2ht, 256, 2048);
    transpose_f16_kernel<<<dim3(10, 64, RELS), 256, 0, stream>>>(fW3, fW3ht, 2048, 320);

    // ---- conv layer 1: CSR gather x -> aggx (50000x192), MFMA -> h1hf ----
    gather_csr_f16_kernel<<<(N_NODES * RELS * 64 + 255) / 256, 256, 0, stream>>>(
        xhf, csr16, browptr, gcursor, aggx_hf, N_NODES);
    gemm_mfma_f16<1, true><<<dim3(1, (N_NODES + 127) / 128, 1), 256, 0, stream>>>(
        aggx_hf, 0, RELS * HID, WcT1, 0, bc1, 0,
        h1hf, 0, HID, nullptr, N_NODES, HID, RELS * HID);

    // ---- conv layer 2 (rows < S only), MFMA -> h2shf ----
    gather_csr_f16_kernel<<<(S_SEEDS * RELS * 64 + 255) / 256, 256, 0, stream>>>(
        h1hf, csr16, browptr, gcursor, agg2hf, S_SEEDS);
    gemm_mfma_f16<1, true><<<dim3(1, S_SEEDS / 128, 1), 256, 0, stream>>>(
        agg2hf, 0, RELS * HID, WcT2, 0, bc2, 0,
        h2shf, 0, HID, nullptr, S_SEEDS, HID, RELS * HID);

    // ---- hs = leaky(h2s @ Wlin + blin) + noise[:S]  (MFMA, f16 out) ----
    gemm_mfma_f16<2, true><<<dim3(1, S_SEEDS / 128, 1), 256, 0, stream>>>(
        h2shf, 0, HID, WlinT, 0, blin, 0,
        hshf, 0, HID, noise, S_SEEDS, HID, HID);

    // ---- d-branch (MFMA): z1 -> z2d -> dhead ----
    gemm_mfma_f16<2, true><<<dim3(2, S_SEEDS / 128, RELS), 256, 0, stream>>>(
        hshf, 0, HID, dW1ht, 256LL * 64, db1, 256,
        z1hf, (long long)S_SEEDS * 256, 256, nullptr, S_SEEDS, 256, HID);
    gemm_mfma_f16<2, false><<<dim3(1, S_SEEDS / 128, RELS), 256, 0, stream>>>(
        z1hf, (long long)S_SEEDS * 256, 256, dW2ht, 32LL * 256, db2, 32,
        z2d, (long long)S_SEEDS * 32, 32, nullptr, S_SEEDS, 32, 256);
    dhead_kernel<<<(RELS * S_SEEDS + 255) / 256, 256, 0, stream>>>(z2d, dW3, db3, out);

    // ---- f-branch (MFMA): z1 -> chunked (fW2, fW3) ----
    gemm_mfma_f16<1, true><<<dim3(2, S_SEEDS / 128, RELS), 256, 0, stream>>>(
        hshf, 0, HID, fW1ht, 256LL * 64, fb1, 256,
        z1hf, (long long)S_SEEDS * 256, 256, nullptr, S_SEEDS, 256, HID);
    for (int c = 0; c < S_SEEDS / S_CH; c++) {
        long long s0 = (long long)c * S_CH;
        gemm_mfma_f16<1, true><<<dim3(2048 / 128, S_CH / 128, RELS), 256, 0, stream>>>(
            z1hf + s0 * 256, (long long)S_SEEDS * 256, 256,
            fW2ht, 2048LL * 256, fb2, 2048,
            z2hf, (long long)S_CH * 2048, 2048, nullptr, S_CH, 2048, 256);
        gemm_mfma_f16<3, false><<<dim3((320 + 127) / 128, S_CH / 128, RELS), 256, 0, stream>>>(
            z2hf, (long long)S_CH * 2048, 2048,
            fW3ht, 320LL * 2048, fb3, 320,
            out + s0 * OUT_COLS + 1, (long long)S_SEEDS * OUT_COLS, OUT_COLS,
            nullptr, S_CH, 320, 2048);
    }
}

// Round 9
// 604.099 us; speedup vs baseline: 2.5298x; 1.1266x over previous
//
#include <hip/hip_runtime.h>
#include <math.h>

// Problem constants (match reference)
#define N_NODES 50000
#define N_EDGES 800000
#define RELS    3
#define HID     64
#define S_SEEDS 8192
#define OUT_COLS 321   // 1 (pred_missing) + 320 (pred_feat)
#define S_CH    4096   // seed-chunk for the 2048-wide f-branch hidden layer
#define NB      391    // buckets of 128 nodes: ceil(50000/128)
#define BCAP    2560   // per-(rel,bucket) edge capacity (mean 2048, +11 sigma)
#define CHUNK   4096   // edges per bin_fill block
#define NCHUNK  196    // ceil(800000/4096)

// fp16 pipeline (values tiny, no range risk; 10 mantissa bits beats bf16's 7 —
// R6 bf16 failed at 0.023; R8 fp16+CSR passed at 0.0039).
typedef __attribute__((ext_vector_type(8))) _Float16 v8h;  // 8 f16 in 4 VGPRs
typedef __attribute__((ext_vector_type(4))) float v4f;     // MFMA accumulator

__device__ __forceinline__ unsigned short f32_to_f16(float f) {
    _Float16 h = (_Float16)f;
    return __builtin_bit_cast(unsigned short, h);
}
__device__ __forceinline__ float f16_to_f32(unsigned short u) {
    return (float)__builtin_bit_cast(_Float16, u);
}

// ---------------------------------------------------------------------------
// fp16 MFMA GEMM: C = act(A @ Bt^T + bias) [+ noise]
// BM=128 rows; BN template {128: 2x2 waves of 64x64, 64: 4x1 waves of 32x64}.
// BN=64 halves tile waste for Nc<=64 shapes (conv/lin) and fits Nc=320 (5x64).
// ACT: 0=none 1=relu 2=leaky(0.01) 3=tanh.
// ---------------------------------------------------------------------------
template<int ACT, bool OUT_F16, int BN>
__global__ __launch_bounds__(256) void gemm_mfma_f16(
    const unsigned short* __restrict__ A, long long sAb, int lda,
    const unsigned short* __restrict__ Bt, long long sBb,
    const float* __restrict__ bias, long long sBiasb,
    void* __restrict__ Cv, long long sCb, int ldc,
    const float* __restrict__ noise,
    int M, int Nc, int K)
{
    constexpr int WC = (BN == 128) ? 2 : 1;     // wave cols
    constexpr int WR = 4 / WC;                  // wave rows
    constexpr int TI = 128 / (WR * 16);         // row frags per wave (4 or 2)
    constexpr int TJ = BN / (WC * 16);          // col frags per wave (4)

    __shared__ __align__(16) unsigned short As[128][40];
    __shared__ __align__(16) unsigned short Bs[BN][40];

    const int r = blockIdx.z;
    A  += (long long)r * sAb;
    Bt += (long long)r * sBb;
    const float* brow = bias ? bias + (long long)r * sBiasb : nullptr;

    const int tid  = threadIdx.x;
    const int wave = tid >> 6, lane = tid & 63;
    const int quad = lane >> 4, l16 = lane & 15;
    const int wrow = (wave / WC) * (TI * 16);
    const int wcol = (wave % WC) * (TJ * 16);
    const int row0 = blockIdx.y * 128, col0 = blockIdx.x * BN;

    v4f acc[TI][TJ] = {};

    const int srow = tid >> 1;            // 0..127
    const int ecol = (tid & 1) * 16;      // each thread stages 16 f16 = 32 B

    for (int k0 = 0; k0 < K; k0 += 32) {
        int gr = row0 + srow;
        int4 a0 = make_int4(0, 0, 0, 0), a1 = make_int4(0, 0, 0, 0);
        if (gr < M) {
            const unsigned short* ap = A + (long long)gr * lda + k0 + ecol;
            a0 = *(const int4*)(ap);
            a1 = *(const int4*)(ap + 8);
        }
        *(int4*)(&As[srow][ecol])     = a0;
        *(int4*)(&As[srow][ecol + 8]) = a1;

        if (tid < 2 * BN) {
            int gn = col0 + srow;
            int4 b0 = make_int4(0, 0, 0, 0), b1 = make_int4(0, 0, 0, 0);
            if (gn < Nc) {
                const unsigned short* bp = Bt + (long long)gn * K + k0 + ecol;
                b0 = *(const int4*)(bp);
                b1 = *(const int4*)(bp + 8);
            }
            *(int4*)(&Bs[srow][ecol])     = b0;
            *(int4*)(&Bs[srow][ecol + 8]) = b1;
        }
        __syncthreads();

        v8h af[TI], bfr[TJ];
#pragma unroll
        for (int i = 0; i < TI; i++)
            af[i] = *(const v8h*)(&As[wrow + i * 16 + l16][quad * 8]);
#pragma unroll
        for (int j = 0; j < TJ; j++)
            bfr[j] = *(const v8h*)(&Bs[wcol + j * 16 + l16][quad * 8]);
#pragma unroll
        for (int i = 0; i < TI; i++)
#pragma unroll
            for (int j = 0; j < TJ; j++)
                acc[i][j] = __builtin_amdgcn_mfma_f32_16x16x32_f16(af[i], bfr[j], acc[i][j], 0, 0, 0);
        __syncthreads();
    }

    float* Cf = (float*)Cv + (long long)r * sCb;
    unsigned short* Ch = (unsigned short*)Cv + (long long)r * sCb;
#pragma unroll
    for (int i = 0; i < TI; i++) {
#pragma unroll
        for (int j = 0; j < TJ; j++) {
            int gc = col0 + wcol + j * 16 + l16;
            if (gc >= Nc) continue;
            float bv = brow ? brow[gc] : 0.f;
#pragma unroll
            for (int t = 0; t < 4; t++) {
                int gr = row0 + wrow + i * 16 + quad * 4 + t;
                if (gr >= M) continue;
                float v = acc[i][j][t] + bv;
                if (ACT == 1)      v = fmaxf(v, 0.f);
                else if (ACT == 2) v = (v > 0.f) ? v : 0.01f * v;
                else if (ACT == 3) v = tanhf(v);
                if (noise) v += noise[(long long)gr * ldc + gc];
                if (OUT_F16) Ch[(long long)gr * ldc + gc] = f32_to_f16(v);
                else         Cf[(long long)gr * ldc + gc] = v;
            }
        }
    }
}

// ---------------------------------------------------------------------------
// Prep kernels
// ---------------------------------------------------------------------------
__global__ void cvt_f32_f16_kernel(const float* __restrict__ src,
                                   unsigned short* __restrict__ dst, long long n)
{
    long long i = (long long)blockIdx.x * blockDim.x + threadIdx.x;
    if (i < n) dst[i] = f32_to_f16(src[i]);
}

// All 8 weight transposes in ONE launch via descriptor table.
// desc: (R, K, N) f32 -> (R, N, K) f16, 32x32 LDS tiles, coalesced both sides.
struct TD { const float* s; unsigned short* d; int K, N, nbx, nby, b0; };
struct TDs { TD v[8]; };

__global__ __launch_bounds__(256) void transpose_all_kernel(TDs ds)
{
    __shared__ float t[32][33];
    int b = blockIdx.x;
    int k = 0;
#pragma unroll
    for (int q = 1; q < 8; q++) if (b >= ds.v[q].b0) k = q;
    TD td = ds.v[k];
    int local = b - td.b0;
    int per_r = td.nbx * td.nby;
    int r  = local / per_r;
    int rem = local - r * per_r;
    int by = rem / td.nbx, bx = rem - by * td.nbx;

    const float* src = td.s + (long long)r * td.K * td.N;
    unsigned short* dst = td.d + (long long)r * td.K * td.N;
    int n0 = bx * 32, k0 = by * 32;
    int tx = threadIdx.x & 31, ty = threadIdx.x >> 5;   // (32, 8)
#pragma unroll
    for (int i = 0; i < 32; i += 8) {
        int kk = k0 + ty + i, n = n0 + tx;
        if (kk < td.K && n < td.N) t[ty + i][tx] = src[(long long)kk * td.N + n];
    }
    __syncthreads();
#pragma unroll
    for (int i = 0; i < 32; i += 8) {
        int n = n0 + ty + i, kk = k0 + tx;
        if (n < td.N && kk < td.K) dst[(long long)n * td.K + kk] = f32_to_f16(t[tx][ty + i]);
    }
}

// ---------------------------------------------------------------------------
// bin_fill: bin edges by dst>>7 into per-(rel,bucket) runs; block-local sort
// + bulk reservation; all global writes are contiguous runs (coalesced).
// Packed entry: (dst&127)<<16 | src  (src < 50000 < 2^16).
// ---------------------------------------------------------------------------
__global__ __launch_bounds__(256) void bin_fill_kernel(
    const int* __restrict__ s0, const int* __restrict__ d0,
    const int* __restrict__ s1, const int* __restrict__ d1,
    const int* __restrict__ s2, const int* __restrict__ d2,
    int* __restrict__ gcursor,            // (RELS*NB), pre-zeroed
    unsigned int* __restrict__ bedges)    // (RELS*NB, BCAP)
{
    __shared__ int cnt[NB];
    __shared__ int lstart[NB];
    __shared__ int fillc[NB];
    __shared__ int gstart[NB];
    __shared__ int scan[512];
    __shared__ unsigned int svals[CHUNK];
    __shared__ short sbuck[CHUNK];

    const int rel = blockIdx.y;
    const int* sp = (rel == 0) ? s0 : (rel == 1) ? s1 : s2;
    const int* dp = (rel == 0) ? d0 : (rel == 1) ? d1 : d2;
    const int tid = threadIdx.x;
    const int e0 = blockIdx.x * CHUNK;
    const int n  = min(CHUNK, N_EDGES - e0);

    for (int i = tid; i < NB; i += 256) { cnt[i] = 0; fillc[i] = 0; }
    __syncthreads();

    int myb[CHUNK / 256];
    unsigned int myv[CHUNK / 256];
#pragma unroll
    for (int i = 0; i < CHUNK / 256; i++) {
        int off = tid + i * 256;
        if (off < n) {
            int e = e0 + off;
            int s = sp[e], d = dp[e];
            int b = d >> 7;
            myb[i] = b;
            myv[i] = ((unsigned int)(d & 127) << 16) | (unsigned int)s;
            atomicAdd(&cnt[b], 1);
        } else myb[i] = -1;
    }
    __syncthreads();

    scan[tid]       = (tid < NB) ? cnt[tid] : 0;
    scan[tid + 256] = (tid + 256 < NB) ? cnt[tid + 256] : 0;
    __syncthreads();
    for (int off = 1; off < 512; off <<= 1) {
        int a = (tid >= off) ? scan[tid - off] : 0;
        int b = (tid + 256 >= off) ? scan[tid + 256 - off] : 0;
        __syncthreads();
        scan[tid] += a; scan[tid + 256] += b;
        __syncthreads();
    }
    if (tid < NB)       lstart[tid]       = scan[tid] - cnt[tid];
    if (tid + 256 < NB) lstart[tid + 256] = scan[tid + 256] - cnt[tid + 256];
    __syncthreads();

#pragma unroll
    for (int i = 0; i < CHUNK / 256; i++) {
        int b = myb[i];
        if (b >= 0) {
            int p = lstart[b] + atomicAdd(&fillc[b], 1);
            svals[p] = myv[i];
            sbuck[p] = (short)b;
        }
    }
    if (tid < NB && cnt[tid] > 0)
        gstart[tid] = atomicAdd(&gcursor[rel * NB + tid], cnt[tid]);
    if (tid + 256 < NB && cnt[tid + 256] > 0)
        gstart[tid + 256] = atomicAdd(&gcursor[rel * NB + tid + 256], cnt[tid + 256]);
    __syncthreads();

    for (int p = tid; p < n; p += 256) {
        int b = sbuck[p];
        int pos = gstart[b] + (p - lstart[b]);
        bedges[(long long)(rel * NB + b) * BCAP + pos] = svals[p];
    }
}

// ---------------------------------------------------------------------------
// bucket_csr: per (rel,bucket) LDS counting sort -> dst-sorted src list (u16)
// + 128 local row starts.
// ---------------------------------------------------------------------------
__global__ __launch_bounds__(256) void bucket_csr_kernel(
    const unsigned int* __restrict__ bedges,
    const int* __restrict__ gcursor,
    unsigned short* __restrict__ csr16,
    int* __restrict__ browptr)
{
    __shared__ int cnt[128], sc[128], start[128], cur[128];
    __shared__ unsigned short ssorted[BCAP];

    const int id  = blockIdx.y * NB + blockIdx.x;
    const int tid = threadIdx.x;
    const int len = gcursor[id];
    const unsigned int* ep = bedges + (long long)id * BCAP;

    for (int i = tid; i < 128; i += 256) cnt[i] = 0;
    __syncthreads();
    for (int i = tid; i < len; i += 256)
        atomicAdd(&cnt[ep[i] >> 16], 1);
    __syncthreads();

    int v = (tid < 128) ? cnt[tid] : 0;
    if (tid < 128) sc[tid] = v;
    __syncthreads();
    for (int off = 1; off < 128; off <<= 1) {
        int a = (tid < 128 && tid >= off) ? sc[tid - off] : 0;
        __syncthreads();
        if (tid < 128) sc[tid] += a;
        __syncthreads();
    }
    if (tid < 128) { start[tid] = sc[tid] - v; cur[tid] = sc[tid] - v; }
    __syncthreads();

    for (int i = tid; i < len; i += 256) {
        unsigned int vv = ep[i];
        int dl = vv >> 16;
        int pos = atomicAdd(&cur[dl], 1);
        ssorted[pos] = (unsigned short)(vv & 0xFFFFu);
    }
    __syncthreads();

    for (int i = tid; i < len; i += 256)
        csr16[(long long)id * BCAP + i] = ssorted[i];
    if (tid < 128) browptr[id * 128 + tid] = start[tid];
}

// ---------------------------------------------------------------------------
// gather_csr_f16: one wave per (node, relation); lane = feature. Register
// accumulation, 8x-unrolled + 4-tail (latency hiding for high-degree rows).
// ---------------------------------------------------------------------------
__global__ __launch_bounds__(256) void gather_csr_f16_kernel(
    const unsigned short* __restrict__ feat,
    const unsigned short* __restrict__ csr16,
    const int* __restrict__ browptr,
    const int* __restrict__ gcursor,
    unsigned short* __restrict__ agg,
    int M)
{
    int w = (blockIdx.x * 256 + threadIdx.x) >> 6;
    int lane = threadIdx.x & 63;
    if (w >= M * RELS) return;
    int r = w % RELS, d = w / RELS;
    int bucket = d >> 7, dl = d & 127;
    int id = r * NB + bucket;
    int p0 = browptr[id * 128 + dl];
    int p1 = (dl == 127) ? gcursor[id] : browptr[id * 128 + dl + 1];
    const unsigned short* cp = csr16 + (long long)id * BCAP;

    float a0 = 0.f, a1 = 0.f, a2 = 0.f, a3 = 0.f;
    float a4 = 0.f, a5 = 0.f, a6 = 0.f, a7 = 0.f;
    int i = p0;
    for (; i + 7 < p1; i += 8) {
        int s0 = cp[i],     s1 = cp[i + 1], s2 = cp[i + 2], s3 = cp[i + 3];
        int s4 = cp[i + 4], s5 = cp[i + 5], s6 = cp[i + 6], s7 = cp[i + 7];
        a0 += f16_to_f32(feat[(long long)s0 * HID + lane]);
        a1 += f16_to_f32(feat[(long long)s1 * HID + lane]);
        a2 += f16_to_f32(feat[(long long)s2 * HID + lane]);
        a3 += f16_to_f32(feat[(long long)s3 * HID + lane]);
        a4 += f16_to_f32(feat[(long long)s4 * HID + lane]);
        a5 += f16_to_f32(feat[(long long)s5 * HID + lane]);
        a6 += f16_to_f32(feat[(long long)s6 * HID + lane]);
        a7 += f16_to_f32(feat[(long long)s7 * HID + lane]);
    }
    if (i + 3 < p1) {
        int s0 = cp[i], s1 = cp[i + 1], s2 = cp[i + 2], s3 = cp[i + 3];
        a0 += f16_to_f32(feat[(long long)s0 * HID + lane]);
        a1 += f16_to_f32(feat[(long long)s1 * HID + lane]);
        a2 += f16_to_f32(feat[(long long)s2 * HID + lane]);
        a3 += f16_to_f32(feat[(long long)s3 * HID + lane]);
        i += 4;
    }
    for (; i < p1; i++) {
        int idx = i - p0;
        float f = f16_to_f32(feat[(long long)cp[i] * HID + lane]);
        if ((idx & 3) == 0) a4 += f; else if ((idx & 3) == 1) a5 += f;
        else if ((idx & 3) == 2) a6 += f; else a7 += f;
    }

    float inv = 1.0f / fmaxf((float)(p1 - p0), 1.0f);
    agg[(long long)d * (RELS * HID) + r * HID + lane] =
        f32_to_f16(((a0 + a1) + (a2 + a3) + (a4 + a5) + (a6 + a7)) * inv);
}

// ---------------------------------------------------------------------------
// d-branch final head: out[r,s,0] = relu(z2d[r,s,:] . dW3[r] + db3[r])
// ---------------------------------------------------------------------------
__global__ void dhead_kernel(const float* __restrict__ z2d,
                             const float* __restrict__ dW3,
                             const float* __restrict__ db3,
                             float* __restrict__ out)
{
    int idx = blockIdx.x * blockDim.x + threadIdx.x;
    if (idx >= RELS * S_SEEDS) return;
    int r = idx / S_SEEDS;
    const float* zp = z2d + (long long)idx * 32;
    const float* wp = dW3 + r * 32;
    float acc = db3[r];
#pragma unroll
    for (int k = 0; k < 32; k++) acc += zp[k] * wp[k];
    out[(long long)idx * OUT_COLS] = fmaxf(acc, 0.f);
}

// ---------------------------------------------------------------------------
extern "C" void kernel_launch(void* const* d_in, const int* in_sizes, int n_in,
                              void* d_out, int out_size, void* d_ws, size_t ws_size,
                              hipStream_t stream)
{
    const float* x     = (const float*)d_in[0];
    const float* noise = (const float*)d_in[1];
    // d_in[2] = seeds: only its shape matters (S=8192); unused.
    const int* srcs[RELS] = { (const int*)d_in[3], (const int*)d_in[5], (const int*)d_in[7] };
    const int* dsts[RELS] = { (const int*)d_in[4], (const int*)d_in[6], (const int*)d_in[8] };
    const float* Wc1  = (const float*)d_in[9];
    const float* bc1  = (const float*)d_in[10];
    const float* Wc2  = (const float*)d_in[11];
    const float* bc2  = (const float*)d_in[12];
    const float* Wlin = (const float*)d_in[13];
    const float* blin = (const float*)d_in[14];
    const float* dW1  = (const float*)d_in[15];
    const float* db1  = (const float*)d_in[16];
    const float* dW2  = (const float*)d_in[17];
    const float* db2  = (const float*)d_in[18];
    const float* dW3  = (const float*)d_in[19];
    const float* db3  = (const float*)d_in[20];
    const float* fW1  = (const float*)d_in[21];
    const float* fb1  = (const float*)d_in[22];
    const float* fW2  = (const float*)d_in[23];
    const float* fb2  = (const float*)d_in[24];
    const float* fW3  = (const float*)d_in[25];
    const float* fb3  = (const float*)d_in[26];
    float* out = (float*)d_out;
    float* w   = (float*)d_ws;

    // ---- workspace layout (4-byte units; ~88.5 MB peak, all 16B-aligned) ----
    int* gcursor = (int*)w;                                     // 1,280
    int* browptr = (int*)(w + 1280);                            // 150,144
    unsigned short* csr16 = (unsigned short*)(w + 151424);      // 1,501,440 f
    unsigned short* aggx_hf = (unsigned short*)(w + 1652864);   // REGION_A
    unsigned int*   bedges  = (unsigned int*)(w + 1652864 + 2400000);
    float*          z2d     = w + 1652864 + 2400000;
    unsigned short* z2hf    = (unsigned short*)(w + 1652864);
    unsigned short* xhf  = (unsigned short*)(w + 14235776);     // REGION_B
    unsigned short* z1hf = (unsigned short*)(w + 14235776);
    unsigned short* h1hf   = (unsigned short*)(w + 17381504);
    unsigned short* agg2hf = (unsigned short*)(w + 18981504);
    unsigned short* h2shf  = (unsigned short*)(w + 19767936);
    unsigned short* hshf   = (unsigned short*)(w + 20030080);
    unsigned short* WcT1   = (unsigned short*)(w + 20292224);
    unsigned short* WcT2   = (unsigned short*)(w + 20298368);
    unsigned short* WlinT  = (unsigned short*)(w + 20304512);
    unsigned short* dW1ht  = (unsigned short*)(w + 20306560);
    unsigned short* dW2ht  = (unsigned short*)(w + 20331136);
    unsigned short* fW1ht  = (unsigned short*)(w + 20343424);
    unsigned short* fW2ht  = (unsigned short*)(w + 20368000);
    unsigned short* fW3ht  = (unsigned short*)(w + 21154432);

    // ---- edge binning + per-bucket CSR ----
    hipMemsetAsync(gcursor, 0, (size_t)RELS * NB * sizeof(int), stream);
    bin_fill_kernel<<<dim3(NCHUNK, RELS), 256, 0, stream>>>(
        srcs[0], dsts[0], srcs[1], dsts[1], srcs[2], dsts[2], gcursor, bedges);
    bucket_csr_kernel<<<dim3(NB, RELS), 256, 0, stream>>>(
        bedges, gcursor, csr16, browptr);

    // ---- prep: x -> f16; all 8 weight transposes in one launch ----
    cvt_f32_f16_kernel<<<(N_NODES * HID + 255) / 256, 256, 0, stream>>>(x, xhf, (long long)N_NODES * HID);
    {
        TDs ds;
        int b0 = 0;
        auto add = [&](int k, const float* s, unsigned short* d, int K, int N, int rels) {
            ds.v[k].s = s; ds.v[k].d = d; ds.v[k].K = K; ds.v[k].N = N;
            ds.v[k].nbx = (N + 31) / 32; ds.v[k].nby = (K + 31) / 32; ds.v[k].b0 = b0;
            b0 += ds.v[k].nbx * ds.v[k].nby * rels;
        };
        add(0, Wc1, WcT1, 192, 64, 1);
        add(1, Wc2, WcT2, 192, 64, 1);
        add(2, Wlin, WlinT, 64, 64, 1);
        add(3, dW1, dW1ht, 64, 256, RELS);
        add(4, dW2, dW2ht, 256, 32, RELS);
        add(5, fW1, fW1ht, 64, 256, RELS);
        add(6, fW2, fW2ht, 256, 2048, RELS);
        add(7, fW3, fW3ht, 2048, 320, RELS);
        transpose_all_kernel<<<b0, 256, 0, stream>>>(ds);
    }

    // ---- conv layer 1: CSR gather x -> aggx (50000x192), MFMA -> h1hf ----
    gather_csr_f16_kernel<<<(N_NODES * RELS * 64 + 255) / 256, 256, 0, stream>>>(
        xhf, csr16, browptr, gcursor, aggx_hf, N_NODES);
    gemm_mfma_f16<1, true, 64><<<dim3(1, (N_NODES + 127) / 128, 1), 256, 0, stream>>>(
        aggx_hf, 0, RELS * HID, WcT1, 0, bc1, 0,
        h1hf, 0, HID, nullptr, N_NODES, HID, RELS * HID);

    // ---- conv layer 2 (rows < S only), MFMA -> h2shf ----
    gather_csr_f16_kernel<<<(S_SEEDS * RELS * 64 + 255) / 256, 256, 0, stream>>>(
        h1hf, csr16, browptr, gcursor, agg2hf, S_SEEDS);
    gemm_mfma_f16<1, true, 64><<<dim3(1, S_SEEDS / 128, 1), 256, 0, stream>>>(
        agg2hf, 0, RELS * HID, WcT2, 0, bc2, 0,
        h2shf, 0, HID, nullptr, S_SEEDS, HID, RELS * HID);

    // ---- hs = leaky(h2s @ Wlin + blin) + noise[:S] ----
    gemm_mfma_f16<2, true, 64><<<dim3(1, S_SEEDS / 128, 1), 256, 0, stream>>>(
        h2shf, 0, HID, WlinT, 0, blin, 0,
        hshf, 0, HID, noise, S_SEEDS, HID, HID);

    // ---- d-branch: z1 -> z2d -> dhead ----
    gemm_mfma_f16<2, true, 128><<<dim3(2, S_SEEDS / 128, RELS), 256, 0, stream>>>(
        hshf, 0, HID, dW1ht, 256LL * 64, db1, 256,
        z1hf, (long long)S_SEEDS * 256, 256, nullptr, S_SEEDS, 256, HID);
    gemm_mfma_f16<2, false, 64><<<dim3(1, S_SEEDS / 128, RELS), 256, 0, stream>>>(
        z1hf, (long long)S_SEEDS * 256, 256, dW2ht, 32LL * 256, db2, 32,
        z2d, (long long)S_SEEDS * 32, 32, nullptr, S_SEEDS, 32, 256);
    dhead_kernel<<<(RELS * S_SEEDS + 255) / 256, 256, 0, stream>>>(z2d, dW3, db3, out);

    // ---- f-branch: z1 -> chunked (fW2, fW3) ----
    gemm_mfma_f16<1, true, 128><<<dim3(2, S_SEEDS / 128, RELS), 256, 0, stream>>>(
        hshf, 0, HID, fW1ht, 256LL * 64, fb1, 256,
        z1hf, (long long)S_SEEDS * 256, 256, nullptr, S_SEEDS, 256, HID);
    for (int c = 0; c < S_SEEDS / S_CH; c++) {
        long long s0 = (long long)c * S_CH;
        gemm_mfma_f16<1, true, 128><<<dim3(2048 / 128, S_CH / 128, RELS), 256, 0, stream>>>(
            z1hf + s0 * 256, (long long)S_SEEDS * 256, 256,
            fW2ht, 2048LL * 256, fb2, 2048,
            z2hf, (long long)S_CH * 2048, 2048, nullptr, S_CH, 2048, 256);
        gemm_mfma_f16<3, false, 64><<<dim3(5, S_CH / 128, RELS), 256, 0, stream>>>(
            z2hf, (long long)S_CH * 2048, 2048,
            fW3ht, 320LL * 2048, fb3, 320,
            out + s0 * OUT_COLS + 1, (long long)S_SEEDS * OUT_COLS, OUT_COLS,
            nullptr, S_CH, 320, 2048);
    }
}